// Round 10
// baseline (128.945 us; speedup 1.0000x reference)
//
#include <hip/hip_runtime.h>
#include <hip/hip_bf16.h>

#define IN_C  32
#define CH    35
#define P_CNT 369
#define NPAIR 64
#define NALL  100000
#define NTILE 6250          // NALL / 16 exactly
#define PP    4             // pairs per wave (grid.y = 64/PP = 16)
#define NWX   256           // waves per y-slice: grid.x(64) * 4 waves/block

// param offsets within a proposal's 369 floats
#define OW1 0               // w1[c][h] = c*8 + h   (c < 35)
#define OB1 280
#define OW2 288             // w2[h][k] = 288 + h*8 + k
#define OB2 352
#define OW3 360
#define OB3 368

// d_ws byte offsets
#define WS_W1F 0            // ushort [64 pair][2 kh][64 lane][8]   131072 B
#define WS_W2F 131072       // ushort [64][64 lane][4]              32768 B
#define WS_B2F 229376       // float  [64][64 lane][4]              65536 B
#define WS_W3F 294912       // float  [64][64 lane][4]              65536 B (fallback only)
#define WS_B3F 360448       // float  [64][2]                       512 B
#define WS_A3F 360960       // ushort [64][64 lane][4]              32768 B (layer3 A-frag)

typedef short  bf16x8 __attribute__((ext_vector_type(8)));
typedef short  bf16x4 __attribute__((ext_vector_type(4)));
typedef float  f32x4  __attribute__((ext_vector_type(4)));

static __device__ inline unsigned short f2bf(float x) {   // software RNE (prep + fallback)
    union { float f; unsigned u; } v; v.f = x;
    unsigned r = v.u + 0x7FFFu + ((v.u >> 16) & 1u);
    return (unsigned short)(r >> 16);
}

// API-sanctioned packed f32->bf16 RNE (native cvt on gfx950).
static __device__ inline unsigned pack2bf(float lo, float hi) {
    __hip_bfloat162 h2 = __float22bfloat162_rn(make_float2(lo, hi));
    union { __hip_bfloat162 h; unsigned u; } c; c.h = h2; return c.u;
}

// ---------------- Prep: params for one pair + lane-exact fragment packing ----
__global__ __launch_bounds__(256) void prep_kernel(
        const float* __restrict__ prop,   // (128, 32)
        const float* __restrict__ W,      // (32, 369)
        const float* __restrict__ b,      // (369,)
        char* __restrict__ ws) {
    const int pp  = blockIdx.x;           // pair index 0..63
    const int tid = threadIdx.x;
    __shared__ float P[2][P_CNT];

    for (int idx = tid; idx < 2 * P_CNT; idx += 256) {
        const int pl = (idx >= P_CNT) ? 1 : 0;
        const int j  = idx - pl * P_CNT;
        const float* pr = prop + (size_t)(2 * pp + pl) * IN_C;
        float acc = b[j];
        #pragma unroll
        for (int c = 0; c < IN_C; ++c)
            acc = fmaf(pr[c], W[(size_t)c * P_CNT + j], acc);
        P[pl][j] = acc;
    }
    __syncthreads();

    if (tid >= 64) return;
    const int lane = tid;
    const int g = lane >> 4;
    const int m = lane & 15;

    // W1F: A-frag of 16x16x32. A[m = h-packed][k = c]; lane: row=m, k=8g+j.
    // k == 35 carries b1 (feature slot 35 is a constant 1.0 in the B-frag).
    {
        unsigned short* w1f = (unsigned short*)(ws + WS_W1F);
        const int pl = m >> 3, h = m & 7;
        #pragma unroll
        for (int kh = 0; kh < 2; ++kh)
            #pragma unroll
            for (int j = 0; j < 8; ++j) {
                const int c = kh * 32 + g * 8 + j;
                float v = 0.f;
                if (c < CH) v = P[pl][OW1 + c * 8 + h];
                else if (c == CH) v = P[pl][OB1 + h];          // bias column
                w1f[((size_t)(pp * 2 + kh) * 64 + lane) * 8 + j] = f2bf(v);
            }
    }
    // W2F: A-frag of 16x16x16 (block-diag packed w2). row=m, k=4g+r
    {
        unsigned short* w2f = (unsigned short*)(ws + WS_W2F);
        const int plj = m >> 3, jj = m & 7;
        #pragma unroll
        for (int r = 0; r < 4; ++r) {
            const int colh = g * 4 + r;
            const int ph = colh >> 3, h = colh & 7;
            const float v = (ph == plj) ? P[plj][OW2 + h * 8 + jj] : 0.f;
            w2f[((size_t)pp * 64 + lane) * 4 + r] = f2bf(v);
        }
    }
    // A3F: A-frag of 16x16x16 for layer 3. A3[m][k]: row 0 = w3 of p_even
    // (k 0..7), row 8 = w3 of p_odd (k 8..15), else 0. lane: m=lane&15, k=4g+r.
    {
        unsigned short* a3f = (unsigned short*)(ws + WS_A3F);
        #pragma unroll
        for (int r = 0; r < 4; ++r) {
            const int kg = g * 4 + r;
            float v = 0.f;
            if (m == 0 && kg < 8)  v = P[0][OW3 + kg];
            if (m == 8 && kg >= 8) v = P[1][OW3 + kg - 8];
            a3f[((size_t)pp * 64 + lane) * 4 + r] = f2bf(v);
        }
    }
    // B2F / W3F: per-lane C-init rows (row = 4g + r, h/j-packed)
    {
        float* b2f = (float*)(ws + WS_B2F);
        float* w3f = (float*)(ws + WS_W3F);
        #pragma unroll
        for (int r = 0; r < 4; ++r) {
            const int row = g * 4 + r;
            b2f[((size_t)pp * 64 + lane) * 4 + r] = P[row >> 3][OB2 + (row & 7)];
            w3f[((size_t)pp * 64 + lane) * 4 + r] = P[row >> 3][OW3 + (row & 7)];
        }
    }
    if (lane < 2) ((float*)(ws + WS_B3F))[pp * 2 + lane] = P[lane][OB3];
}

// Load one 16-row feature tile's B-fragments for this lane.
// bf0: k = 8g+j (c 0..31); bf1: k = 32+8g+j — g==0 holds c 32..34 plus the
// constant 1.0 at k==35 that multiplies the bias column of W1F.
#define LOAD_TILE(T, O0, O1) do {                                             \
    const float* fr_ = allf + (size_t)((T) * 16 + col) * CH;                  \
    const float v0_ = fr_[g * 8 + 0], v1_ = fr_[g * 8 + 1];                   \
    const float v2_ = fr_[g * 8 + 2], v3_ = fr_[g * 8 + 3];                   \
    const float v4_ = fr_[g * 8 + 4], v5_ = fr_[g * 8 + 5];                   \
    const float v6_ = fr_[g * 8 + 6], v7_ = fr_[g * 8 + 7];                   \
    float e0_ = 0.f, e1_ = 0.f, e2_ = 0.f, e3_ = 0.f;                         \
    if (g == 0) { e0_ = fr_[32]; e1_ = fr_[33]; e2_ = fr_[34]; e3_ = 1.f; }   \
    union { unsigned u[4]; bf16x8 v; } A0_, A1_;                              \
    A0_.u[0] = pack2bf(v0_, v1_); A0_.u[1] = pack2bf(v2_, v3_);               \
    A0_.u[2] = pack2bf(v4_, v5_); A0_.u[3] = pack2bf(v6_, v7_);               \
    A1_.u[0] = pack2bf(e0_, e1_); A1_.u[1] = pack2bf(e2_, e3_);               \
    A1_.u[2] = 0u; A1_.u[3] = 0u;                                             \
    O0 = A0_.v; O1 = A1_.v; } while (0)

// ---------------- Main: weights-resident (PP pairs), persistent tile stream -
// All resident per-pair values are EXCLUSIVELY MFMA operands (A or C):
// AGPR parking is free (MFMA reads AGPRs natively) — no accvgpr shuttles.
// Layer 3 is a 4th MFMA (A3 = w3 block-diag), killing the per-unit
// shfl_xor (30-cyc DS latency) + fma chain of R9's VALU epilogue.
__global__ __launch_bounds__(256, 4) void mlp_kernel(
        const float* __restrict__ allf,   // (100000, 35)
        const char* __restrict__ ws,
        float* __restrict__ out) {        // (128, 100000)
    const int lane = threadIdx.x & 63;
    const int wave = threadIdx.x >> 6;
    const int wx   = blockIdx.x * 4 + wave;   // 0..NWX-1
    const int g    = lane >> 4;
    const int col  = lane & 15;
    const int ppbase = blockIdx.y * PP;

    const bf16x8* __restrict__ w1f = (const bf16x8*)(ws + WS_W1F);
    const bf16x4* __restrict__ w2f = (const bf16x4*)(ws + WS_W2F);
    const bf16x4* __restrict__ a3f = (const bf16x4*)(ws + WS_A3F);
    const f32x4*  __restrict__ b2f = (const f32x4*)(ws + WS_B2F);
    const float*  __restrict__ b3f = (const float*)(ws + WS_B3F);

    // ---- resident weights for PP pairs, loaded once ----
    bf16x8 w1a[PP], w1b[PP];
    bf16x4 w2v[PP], a3v[PP];
    f32x4  b2v[PP], b3v[PP];
    #pragma unroll
    for (int i = 0; i < PP; ++i) {
        const int pp = ppbase + i;
        w1a[i] = w1f[(pp * 2 + 0) * 64 + lane];
        w1b[i] = w1f[(pp * 2 + 1) * 64 + lane];
        w2v[i] = w2f[pp * 64 + lane];
        a3v[i] = a3f[pp * 64 + lane];
        b2v[i] = b2f[pp * 64 + lane];
        const float b3e = b3f[pp * 2 + 0], b3o = b3f[pp * 2 + 1];
        b3v[i] = (f32x4){ (g == 0) ? b3e : ((g == 2) ? b3o : 0.f), 0.f, 0.f, 0.f };
    }
    #pragma unroll
    for (int i = 0; i < PP; ++i)
        asm volatile("" : "+v"(w1a[i]), "+v"(w1b[i]), "+v"(w2v[i]),
                          "+v"(a3v[i]), "+v"(b2v[i]), "+v"(b3v[i]));

    if (wx >= NTILE) return;

    // ---- stream tiles with 1-deep prefetch ----
    bf16x8 cb0, cb1, nb0, nb1;
    LOAD_TILE(wx, cb0, cb1);

    #pragma unroll 1
    for (int t = wx; t < NTILE; t += NWX) {
        const int tn = (t + NWX < NTILE) ? (t + NWX) : t;   // clamped prefetch
        LOAD_TILE(tn, nb0, nb1);

        #pragma unroll
        for (int i = 0; i < PP; ++i) {
            // ---- layer 1 (+bias via k=35): C1[h-packed row, a]; rows 4g+r
            f32x4 c1 = {0.f, 0.f, 0.f, 0.f};
            c1 = __builtin_amdgcn_mfma_f32_16x16x32_bf16(w1a[i], cb0, c1, 0, 0, 0);
            c1 = __builtin_amdgcn_mfma_f32_16x16x32_bf16(w1b[i], cb1, c1, 0, 0, 0);

#if __has_builtin(__builtin_amdgcn_mfma_f32_16x16x16bf16_1k)
            // ---- layer 2: C1 output layout == 16x16x16 B-fragment layout
            union { unsigned u[2]; bf16x4 v; } pb;
            pb.u[0] = pack2bf(fmaxf(c1[0], 0.f), fmaxf(c1[1], 0.f));
            pb.u[1] = pack2bf(fmaxf(c1[2], 0.f), fmaxf(c1[3], 0.f));
            f32x4 c2 = __builtin_amdgcn_mfma_f32_16x16x16bf16_1k(w2v[i], pb.v, b2v[i], 0, 0, 0);

            // ---- layer 3 as MFMA: C2 layout == B-fragment layout again.
            // C3[0][a] (g==0 lanes, reg0) = p_even out; C3[8][a] (g==2, reg0)
            // = p_odd out; b3 pre-folded into the C-init b3v.
            union { unsigned u[2]; bf16x4 v; } pc;
            pc.u[0] = pack2bf(fmaxf(c2[0], 0.f), fmaxf(c2[1], 0.f));
            pc.u[1] = pack2bf(fmaxf(c2[2], 0.f), fmaxf(c2[3], 0.f));
            f32x4 c3 = __builtin_amdgcn_mfma_f32_16x16x16bf16_1k(a3v[i], pc.v, b3v[i], 0, 0, 0);

            if (!(g & 1)) {
                const int pl = lane >> 5;               // 0: p even, 1: p odd
                out[(size_t)((ppbase + i) * 2 + pl) * NALL + t * 16 + col] = c3[0];
            }
#else
            // ---- fallback (not taken on gfx950): shfl redistribution + x32
            // MFMA for layer 2, scalar VALU epilogue for layer 3.
            const f32x4 w3vv = ((const f32x4*)(ws + WS_W3F))[(ppbase + i) * 64 + lane];
            float rl[4];
            #pragma unroll
            for (int r = 0; r < 4; ++r) rl[r] = fmaxf(c1[r], 0.f);
            bf16x8 pb8;
            #pragma unroll
            for (int j = 0; j < 8; ++j) {
                const int src = ((2 * g + (j >> 2)) << 4) + col;
                pb8[j] = (short)f2bf(__shfl(rl[j & 3], src, 64));
            }
            bf16x8 w28;
            #pragma unroll
            for (int r = 0; r < 4; ++r) { w28[r] = w2v[i][r]; w28[r + 4] = 0; }
            f32x4 c2 = __builtin_amdgcn_mfma_f32_16x16x32_bf16(w28, pb8, b2v[i], 0, 0, 0);
            float s;
            s = fmaf(fmaxf(c2[0], 0.f), w3vv[0], 0.f);
            s = fmaf(fmaxf(c2[1], 0.f), w3vv[1], s);
            s = fmaf(fmaxf(c2[2], 0.f), w3vv[2], s);
            s = fmaf(fmaxf(c2[3], 0.f), w3vv[3], s);
            const float tv = s + __shfl_xor(s, 16, 64);
            if (!(g & 1)) {
                const int pl = lane >> 5;
                out[(size_t)((ppbase + i) * 2 + pl) * NALL + t * 16 + col] =
                    tv + b3f[(ppbase + i) * 2 + pl];
            }
#endif
        }
        cb0 = nb0; cb1 = nb1;
    }
}

extern "C" void kernel_launch(void* const* d_in, const int* in_sizes, int n_in,
                              void* d_out, int out_size, void* d_ws, size_t ws_size,
                              hipStream_t stream) {
    const float* prop = (const float*)d_in[0];   // (128, 32)
    const float* allf = (const float*)d_in[1];   // (100000, 35)
    const float* W    = (const float*)d_in[2];   // (32, 369)
    const float* b    = (const float*)d_in[3];   // (369,)
    float* out = (float*)d_out;                  // (128, 100000, 1)
    char*  ws  = (char*)d_ws;

    prep_kernel<<<NPAIR, 256, 0, stream>>>(prop, W, b, ws);

    // Persistent: 64 blocks x 16 pair-quarters = 1024 blocks = exactly
    // 4 blocks/CU capacity at 4 waves/SIMD -> no dispatch tail.
    dim3 grid(64, NPAIR / PP);
    mlp_kernel<<<grid, 256, 0, stream>>>(allf, ws, out);
}

// Round 12
// 122.854 us; speedup vs baseline: 1.0496x; 1.0496x over previous
//
#include <hip/hip_runtime.h>
#include <hip/hip_bf16.h>

#define IN_C  32
#define CH    35
#define P_CNT 369
#define NPAIR 64
#define NALL  100000
#define NTILE 6250          // NALL / 16 exactly
#define PP    4             // pairs per wave (grid.y = 64/PP = 16)
#define NWX   512           // waves per y-slice: grid.x(128) * 4 waves/block

// param offsets within a proposal's 369 floats
#define OW1 0               // w1[c][h] = c*8 + h   (c < 35)
#define OB1 280
#define OW2 288             // w2[h][k] = 288 + h*8 + k
#define OB2 352
#define OW3 360
#define OB3 368

// d_ws byte offsets
#define WS_W1F 0            // ushort [64 pair][2 kh][64 lane][8]   131072 B
#define WS_W2F 131072       // ushort [64][64 lane][4]              32768 B
#define WS_B2F 229376       // float  [64][64 lane][4]              65536 B
#define WS_W3F 294912       // float  [64][64 lane][4]              65536 B (fallback only)
#define WS_B3F 360448       // float  [64][2]                       512 B
#define WS_A3F 360960       // ushort [64][64 lane][4]              32768 B (layer3 A-frag)
#define WS_F0  524288       // ushort [6250 tile][64 lane][8]       6,400,000 B (feat frag lo)
#define WS_F1  6924288      // uint   [6250 tile][16 col][2]        800,000 B  (feat frag hi)
#define WS_NEED 7724288

typedef short  bf16x8 __attribute__((ext_vector_type(8)));
typedef short  bf16x4 __attribute__((ext_vector_type(4)));
typedef float  f32x4  __attribute__((ext_vector_type(4)));
typedef unsigned u32x2 __attribute__((ext_vector_type(2)));

#define MFMA32 __builtin_amdgcn_mfma_f32_16x16x32_bf16
#if __has_builtin(__builtin_amdgcn_mfma_f32_16x16x16bf16_1k)
#define HAVE_1K 1
#define MFMA16 __builtin_amdgcn_mfma_f32_16x16x16bf16_1k
#else
#define HAVE_1K 0
#endif

static __device__ inline unsigned short f2bf(float x) {   // software RNE (prep + fallback)
    union { float f; unsigned u; } v; v.f = x;
    unsigned r = v.u + 0x7FFFu + ((v.u >> 16) & 1u);
    return (unsigned short)(r >> 16);
}

// API-sanctioned packed f32->bf16 RNE (native cvt on gfx950).
static __device__ inline unsigned pack2bf(float lo, float hi) {
    __hip_bfloat162 h2 = __float22bfloat162_rn(make_float2(lo, hi));
    union { __hip_bfloat162 h; unsigned u; } c; c.h = h2; return c.u;
}

// ---------------- Prep A: params for one pair + lane-exact fragment packing --
__global__ __launch_bounds__(256) void prep_kernel(
        const float* __restrict__ prop,   // (128, 32)
        const float* __restrict__ W,      // (32, 369)
        const float* __restrict__ b,      // (369,)
        char* __restrict__ ws) {
    const int pp  = blockIdx.x;           // pair index 0..63
    const int tid = threadIdx.x;
    __shared__ float P[2][P_CNT];

    for (int idx = tid; idx < 2 * P_CNT; idx += 256) {
        const int pl = (idx >= P_CNT) ? 1 : 0;
        const int j  = idx - pl * P_CNT;
        const float* pr = prop + (size_t)(2 * pp + pl) * IN_C;
        float acc = b[j];
        #pragma unroll
        for (int c = 0; c < IN_C; ++c)
            acc = fmaf(pr[c], W[(size_t)c * P_CNT + j], acc);
        P[pl][j] = acc;
    }
    __syncthreads();

    if (tid >= 64) return;
    const int lane = tid;
    const int g = lane >> 4;
    const int m = lane & 15;

    // W1F: A-frag of 16x16x32. A[m = h-packed][k = c]; k==35 carries b1.
    {
        unsigned short* w1f = (unsigned short*)(ws + WS_W1F);
        const int pl = m >> 3, h = m & 7;
        #pragma unroll
        for (int kh = 0; kh < 2; ++kh)
            #pragma unroll
            for (int j = 0; j < 8; ++j) {
                const int c = kh * 32 + g * 8 + j;
                float v = 0.f;
                if (c < CH) v = P[pl][OW1 + c * 8 + h];
                else if (c == CH) v = P[pl][OB1 + h];          // bias column
                w1f[((size_t)(pp * 2 + kh) * 64 + lane) * 8 + j] = f2bf(v);
            }
    }
    // W2F: A-frag of 16x16x16 (block-diag packed w2). row=m, k=4g+r
    {
        unsigned short* w2f = (unsigned short*)(ws + WS_W2F);
        const int plj = m >> 3, jj = m & 7;
        #pragma unroll
        for (int r = 0; r < 4; ++r) {
            const int colh = g * 4 + r;
            const int ph = colh >> 3, h = colh & 7;
            const float v = (ph == plj) ? P[plj][OW2 + h * 8 + jj] : 0.f;
            w2f[((size_t)pp * 64 + lane) * 4 + r] = f2bf(v);
        }
    }
    // A3F: layer-3 A-frag. row0 k0..7 = w3 p_even; row8 k8..15 = w3 p_odd.
    {
        unsigned short* a3f = (unsigned short*)(ws + WS_A3F);
        #pragma unroll
        for (int r = 0; r < 4; ++r) {
            const int kg = g * 4 + r;
            float v = 0.f;
            if (m == 0 && kg < 8)  v = P[0][OW3 + kg];
            if (m == 8 && kg >= 8) v = P[1][OW3 + kg - 8];
            a3f[((size_t)pp * 64 + lane) * 4 + r] = f2bf(v);
        }
    }
    // B2F / W3F: per-lane C-init rows (row = 4g + r)
    {
        float* b2f = (float*)(ws + WS_B2F);
        float* w3f = (float*)(ws + WS_W3F);
        #pragma unroll
        for (int r = 0; r < 4; ++r) {
            const int row = g * 4 + r;
            b2f[((size_t)pp * 64 + lane) * 4 + r] = P[row >> 3][OB2 + (row & 7)];
            w3f[((size_t)pp * 64 + lane) * 4 + r] = P[row >> 3][OW3 + (row & 7)];
        }
    }
    if (lane < 2) ((float*)(ws + WS_B3F))[pp * 2 + lane] = P[lane][OB3];
}

// ---------------- Prep B: prepack features into fragment-ordered bf16 -------
// One wave per 16-row tile. mlp's tile load becomes 1 dwordx4 + 1 8B load.
__global__ __launch_bounds__(256) void prep_feat(
        const float* __restrict__ allf, char* __restrict__ ws) {
    const int lane = threadIdx.x & 63;
    const int tile = blockIdx.x * 4 + (threadIdx.x >> 6);
    if (tile >= NTILE) return;
    const int g = lane >> 4, col = lane & 15;
    const float* fr = allf + (size_t)(tile * 16 + col) * CH;
    union { unsigned u[4]; bf16x8 v; } A;
    A.u[0] = pack2bf(fr[g * 8 + 0], fr[g * 8 + 1]);
    A.u[1] = pack2bf(fr[g * 8 + 2], fr[g * 8 + 3]);
    A.u[2] = pack2bf(fr[g * 8 + 4], fr[g * 8 + 5]);
    A.u[3] = pack2bf(fr[g * 8 + 6], fr[g * 8 + 7]);
    ((bf16x8*)(ws + WS_F0))[(size_t)tile * 64 + lane] = A.v;
    if (g == 0) {
        unsigned* dst = (unsigned*)(ws + WS_F1) + ((size_t)tile * 16 + col) * 2;
        dst[0] = pack2bf(fr[32], fr[33]);
        dst[1] = pack2bf(fr[34], 1.0f);      // 1.0 multiplies the b1 column (k=35)
    }
}

// Fallback tile load (ws too small for prepack): 11 scalar loads + cvt.
#define LOAD_TILE_FB(T, O0, O1) do {                                          \
    const float* fr_ = allf + (size_t)((T) * 16 + col) * CH;                  \
    const float v0_ = fr_[g * 8 + 0], v1_ = fr_[g * 8 + 1];                   \
    const float v2_ = fr_[g * 8 + 2], v3_ = fr_[g * 8 + 3];                   \
    const float v4_ = fr_[g * 8 + 4], v5_ = fr_[g * 8 + 5];                   \
    const float v6_ = fr_[g * 8 + 6], v7_ = fr_[g * 8 + 7];                   \
    float e0_ = 0.f, e1_ = 0.f, e2_ = 0.f, e3_ = 0.f;                         \
    if (g == 0) { e0_ = fr_[32]; e1_ = fr_[33]; e2_ = fr_[34]; e3_ = 1.f; }   \
    union { unsigned u[4]; bf16x8 v; } A0_, A1_;                              \
    A0_.u[0] = pack2bf(v0_, v1_); A0_.u[1] = pack2bf(v2_, v3_);               \
    A0_.u[2] = pack2bf(v4_, v5_); A0_.u[3] = pack2bf(v6_, v7_);               \
    A1_.u[0] = pack2bf(e0_, e1_); A1_.u[1] = pack2bf(e2_, e3_);               \
    A1_.u[2] = 0u; A1_.u[3] = 0u;                                             \
    O0 = A0_.v; O1 = A1_.v; } while (0)

#define BUILD_HI(E, O1) do {                                                  \
    union { unsigned u[4]; bf16x8 v; } B_;                                    \
    B_.u[0] = (g == 0) ? (E)[0] : 0u; B_.u[1] = (g == 0) ? (E)[1] : 0u;       \
    B_.u[2] = 0u; B_.u[3] = 0u; O1 = B_.v; } while (0)

// ---------------- Main: weights-resident, 2-chain staged ILP, tile stream ---
template<bool PRE>
__global__ __launch_bounds__(256, 4) void mlp_kernel(
        const float* __restrict__ allf,   // (100000, 35)
        const char* __restrict__ ws,
        float* __restrict__ out) {        // (128, 100000)
    const int lane = threadIdx.x & 63;
    const int wx   = blockIdx.x * 4 + (threadIdx.x >> 6);   // 0..NWX-1
    const int g    = lane >> 4;
    const int col  = lane & 15;
    const int ppbase = blockIdx.y * PP;

    const bf16x8* __restrict__ w1f = (const bf16x8*)(ws + WS_W1F);
    const bf16x4* __restrict__ w2f = (const bf16x4*)(ws + WS_W2F);
    const bf16x4* __restrict__ a3f = (const bf16x4*)(ws + WS_A3F);
    const f32x4*  __restrict__ b2f = (const f32x4*)(ws + WS_B2F);
    const float*  __restrict__ b3f = (const float*)(ws + WS_B3F);
    const bf16x8* __restrict__ f0  = (const bf16x8*)(ws + WS_F0);
    const u32x2*  __restrict__ f1  = (const u32x2*)(ws + WS_F1);

    // resident weights for PP pairs (~68 regs), loaded once
    bf16x8 w1a[PP], w1b[PP];
    bf16x4 w2v[PP], a3v[PP];
    f32x4  b2v[PP];
    float  b3s[PP];
    #pragma unroll
    for (int i = 0; i < PP; ++i) {
        const int pp = ppbase + i;
        w1a[i] = w1f[(pp * 2 + 0) * 64 + lane];
        w1b[i] = w1f[(pp * 2 + 1) * 64 + lane];
        w2v[i] = w2f[pp * 64 + lane];
        a3v[i] = a3f[pp * 64 + lane];
        b2v[i] = b2f[pp * 64 + lane];
        b3s[i] = b3f[pp * 2 + (lane >> 5)];
    }

    bf16x8 cb0, cb1, pf0, pf1;
    u32x2  pfe;
    if (PRE) {
        cb0 = f0[(size_t)wx * 64 + lane];
        u32x2 e = f1[(size_t)wx * 16 + col];
        BUILD_HI(e, cb1);
    } else {
        LOAD_TILE_FB(wx, cb0, cb1);
    }

    #pragma unroll 1
    for (int t = wx; t < NTILE; t += NWX) {
        const int tn = (t + NWX < NTILE) ? (t + NWX) : t;   // clamped prefetch
        if (PRE) {
            pf0 = f0[(size_t)tn * 64 + lane];
            pfe = f1[(size_t)tn * 16 + col];
        } else {
            LOAD_TILE_FB(tn, pf0, pf1);
        }

#if HAVE_1K
        // two staged passes of 2 independent pair-chains each
        #pragma unroll
        for (int q = 0; q < 2; ++q) {
            const int i0 = 2 * q, i1 = 2 * q + 1;
            f32x4 z = {0.f, 0.f, 0.f, 0.f};
            f32x4 c1a = z, c1b = z;
            c1a = MFMA32(w1a[i0], cb0, c1a, 0, 0, 0);
            c1b = MFMA32(w1a[i1], cb0, c1b, 0, 0, 0);
            c1a = MFMA32(w1b[i0], cb1, c1a, 0, 0, 0);
            c1b = MFMA32(w1b[i1], cb1, c1b, 0, 0, 0);
            union { unsigned u[2]; bf16x4 v; } pba, pbb;
            pba.u[0] = pack2bf(fmaxf(c1a[0], 0.f), fmaxf(c1a[1], 0.f));
            pbb.u[0] = pack2bf(fmaxf(c1b[0], 0.f), fmaxf(c1b[1], 0.f));
            pba.u[1] = pack2bf(fmaxf(c1a[2], 0.f), fmaxf(c1a[3], 0.f));
            pbb.u[1] = pack2bf(fmaxf(c1b[2], 0.f), fmaxf(c1b[3], 0.f));
            f32x4 c2a = MFMA16(w2v[i0], pba.v, b2v[i0], 0, 0, 0);
            f32x4 c2b = MFMA16(w2v[i1], pbb.v, b2v[i1], 0, 0, 0);
            union { unsigned u[2]; bf16x4 v; } pca, pcb;
            pca.u[0] = pack2bf(fmaxf(c2a[0], 0.f), fmaxf(c2a[1], 0.f));
            pcb.u[0] = pack2bf(fmaxf(c2b[0], 0.f), fmaxf(c2b[1], 0.f));
            pca.u[1] = pack2bf(fmaxf(c2a[2], 0.f), fmaxf(c2a[3], 0.f));
            pcb.u[1] = pack2bf(fmaxf(c2b[2], 0.f), fmaxf(c2b[3], 0.f));
            f32x4 c3a = MFMA16(a3v[i0], pca.v, z, 0, 0, 0);
            f32x4 c3b = MFMA16(a3v[i1], pcb.v, z, 0, 0, 0);
            if (!(g & 1)) {
                const int pl = lane >> 5;               // 0: p even, 1: p odd
                out[(size_t)((ppbase + i0) * 2 + pl) * NALL + t * 16 + col] = c3a[0] + b3s[i0];
                out[(size_t)((ppbase + i1) * 2 + pl) * NALL + t * 16 + col] = c3b[0] + b3s[i1];
            }
        }
#else
        // fallback (not taken on gfx950): shfl redistribution + x32 MFMA + VALU L3
        #pragma unroll
        for (int i = 0; i < PP; ++i) {
            f32x4 c1 = {0.f, 0.f, 0.f, 0.f};
            c1 = MFMA32(w1a[i], cb0, c1, 0, 0, 0);
            c1 = MFMA32(w1b[i], cb1, c1, 0, 0, 0);
            const f32x4 w3vv = ((const f32x4*)(ws + WS_W3F))[(ppbase + i) * 64 + lane];
            float rl[4];
            #pragma unroll
            for (int r = 0; r < 4; ++r) rl[r] = fmaxf(c1[r], 0.f);
            bf16x8 pb8;
            #pragma unroll
            for (int j = 0; j < 8; ++j) {
                const int src = ((2 * g + (j >> 2)) << 4) + col;
                pb8[j] = (short)f2bf(__shfl(rl[j & 3], src, 64));
            }
            bf16x8 w28;
            #pragma unroll
            for (int r = 0; r < 4; ++r) { w28[r] = w2v[i][r]; w28[r + 4] = 0; }
            f32x4 c2 = MFMA32(w28, pb8, b2v[i], 0, 0, 0);
            float s;
            s = fmaf(fmaxf(c2[0], 0.f), w3vv[0], 0.f);
            s = fmaf(fmaxf(c2[1], 0.f), w3vv[1], s);
            s = fmaf(fmaxf(c2[2], 0.f), w3vv[2], s);
            s = fmaf(fmaxf(c2[3], 0.f), w3vv[3], s);
            const float tv = s + __shfl_xor(s, 16, 64);
            if (!(g & 1)) {
                const int pl = lane >> 5;
                out[(size_t)((ppbase + i) * 2 + pl) * NALL + t * 16 + col] = tv + b3s[i];
            }
        }
#endif
        cb0 = pf0;
        if (PRE) { BUILD_HI(pfe, cb1); } else { cb1 = pf1; }
    }
}

extern "C" void kernel_launch(void* const* d_in, const int* in_sizes, int n_in,
                              void* d_out, int out_size, void* d_ws, size_t ws_size,
                              hipStream_t stream) {
    const float* prop = (const float*)d_in[0];   // (128, 32)
    const float* allf = (const float*)d_in[1];   // (100000, 35)
    const float* W    = (const float*)d_in[2];   // (32, 369)
    const float* b    = (const float*)d_in[3];   // (369,)
    float* out = (float*)d_out;                  // (128, 100000, 1)
    char*  ws  = (char*)d_ws;

    prep_kernel<<<NPAIR, 256, 0, stream>>>(prop, W, b, ws);

    dim3 grid(128, NPAIR / PP);                  // 2048 blocks
    if (ws_size >= (size_t)WS_NEED) {
        prep_feat<<<(NTILE + 3) / 4, 256, 0, stream>>>(allf, ws);
        mlp_kernel<true><<<grid, 256, 0, stream>>>(allf, ws, out);
    } else {
        mlp_kernel<false><<<grid, 256, 0, stream>>>(allf, ws, out);
    }
}